// Round 12
// baseline (52.619 us; speedup 1.0000x reference)
//
#include <hip/hip_runtime.h>
#include <hip/hip_bf16.h>
#include <math.h>

#define B 16
#define V 100000
#define S 4096
#define BS (B * S)      // 65536
#define NT 512
#define JP 16           // dst panels of 256 rows
#define ONE_BF 0x3F80u  // 1.0 in bf16

typedef __attribute__((ext_vector_type(8))) short bf16x8;
typedef __attribute__((ext_vector_type(16))) float f32x16;

static __device__ __forceinline__ unsigned bft(float x) {
  return __float_as_uint(x) >> 16;  // truncating f32 -> bf16 bits
}
static __device__ __forceinline__ float bff(unsigned hbits) {
  return __uint_as_float(hbits << 16);
}
static __device__ __forceinline__ unsigned pk(unsigned lo, unsigned hi) {
  return (lo & 0xFFFFu) | (hi << 16);
}

// ws layout (floats):
//   part_src[16][BS] @ 0       (4 MB)
//   part_dst[4][BS]  @ 16*BS   (1 MB)
//   srcfrag          @ 21*BS   (2 MB)  B-side fragments, tile-swizzled
//   dstfrag          @ 29*BS   (2 MB)  A-side fragments, [point][h] uint4
//
// R12 = R11 byte-identical EXCEPT the mfma kernel is launched TWICE
// (idempotent plane writes) -> delta vs R11's 33.2 us measures T_mfma
// directly, since the rocprof top-5 never shows our kernels.

// ---------------------------------------------------------------------------
// Prep kernel: per-point fragment content computed ONCE. src -> B-fragments
// laid out exactly as the mfma kernel's LDS wants them (staging = memcpy).
// dst -> A-fragment uint4 pair. Thread 0 zeroes the output scalar.
// ---------------------------------------------------------------------------
__global__ __launch_bounds__(NT) void chamfer_prep_kernel(
    const float* __restrict__ src_verts, const float* __restrict__ dst_verts,
    const int* __restrict__ src_idx, const int* __restrict__ dst_idx,
    uint2* __restrict__ srcfrag, uint4* __restrict__ dstfrag,
    float* __restrict__ out) {
  int t = blockIdx.x * NT + threadIdx.x;  // 0 .. 2*BS-1 (set uniform per block)
  if (t == 0) *out = 0.f;
  int set = t >> 16;
  int i = t & (BS - 1);  // b*S + p
  int b = i >> 12;

  const int* idx = set ? dst_idx : src_idx;
  const float* verts = set ? dst_verts : src_verts;
  int v = idx[i];
  v = v < 0 ? 0 : (v >= V ? V - 1 : v);
  const float* pv = verts + ((size_t)b * V + v) * 3;
  float x = pv[0], y = pv[1], z = pv[2];
  unsigned hx = bft(x), hy = bft(y), hz = bft(z);
  float n2 = x * x + y * y + z * z;
  unsigned n2h = bft(n2);
  unsigned n2l = bft(n2 - bff(n2h));

  if (set == 0) {
    // B-side (src): k0-7 = [hx,hy,hz,lx,ly,lz,hx,hy], k8-15 = [hz,s2h,s2l,1,1,0,0,0]
    unsigned lx = bft(x - bff(hx)), ly = bft(y - bff(hy)), lz = bft(z - bff(hz));
    int tile = i >> 5, c = i & 31;
    uint2* base = srcfrag + (size_t)tile * 128;  // 1024 B per tile
    base[c]      = make_uint2(pk(hx, hy), pk(hz, lx));        // h=0 dw 0-1
    base[64 + c] = make_uint2(pk(ly, lz), pk(hx, hy));        // h=0 dw 2-3
    base[32 + c] = make_uint2(pk(hz, n2h), pk(n2l, ONE_BF));  // h=1 dw 0-1
    base[96 + c] = make_uint2(pk(ONE_BF, 0u), 0u);            // h=1 dw 2-3
  } else {
    // A-side (dst): k0-7 = [mx,my,mz,mx,my,mz,nx,ny], k8-15 = [nz,1,1,d2h,d2l,0,0,0]
    unsigned mx = bft(-2.f * bff(hx)), my = bft(-2.f * bff(hy)), mz = bft(-2.f * bff(hz));
    unsigned nx = bft(-2.f * (x - bff(hx)));
    unsigned ny = bft(-2.f * (y - bff(hy)));
    unsigned nz = bft(-2.f * (z - bff(hz)));
    dstfrag[(size_t)i * 2]     = make_uint4(pk(mx, my), pk(mz, mx), pk(my, mz), pk(nx, ny));
    dstfrag[(size_t)i * 2 + 1] = make_uint4(pk(nz, ONE_BF), pk(ONE_BF, n2h), pk(n2l, 0u), 0u);
  }
}

// ---------------------------------------------------------------------------
// Fused kernel: block = (b, jp of 256 dst rows, iq of 1024 src). 8 waves,
// one 32-row dst tile per wave; per-wave rotated tile order.
// ---------------------------------------------------------------------------
__global__ __launch_bounds__(NT, 4) void chamfer_mfma_kernel(
    const uint4* __restrict__ srcfrag4, const uint4* __restrict__ dstfrag,
    float* __restrict__ part_src, float* __restrict__ part_dst) {
  __shared__ struct {
    uint4 sfrag[2048];   // 32 KB: 32 tiles x 1024 B
    unsigned smin[1024]; // 4 KB
  } sh;
  // epilogue overlay: 256 rows x stride 33 floats = 33792 B (sfrag + smin head)
  float* red = (float*)sh.sfrag;

  int bid = blockIdx.x;
  int b = bid >> 6;
  int jp = (bid >> 2) & 15;
  int iq = bid & 3;
  int tid = threadIdx.x;

  // ---- stage: straight coalesced copy of this quarter's fragment chunk
  const uint4* chunk = srcfrag4 + (size_t)(b * S + iq * 1024) * 2;  // 32 KB
  #pragma unroll
  for (int k = 0; k < 4; ++k) {
    sh.sfrag[tid + k * NT] = chunk[tid + k * NT];
  }
  for (int p = tid; p < 1024; p += NT) sh.smin[p] = 0x7F800000u;  // +INF

  // ---- A-fragment: load of my dst row's half
  int w = tid >> 6;
  int lane = tid & 63;
  int c = lane & 31, h = lane >> 5;
  int gj = b * S + jp * 256 + w * 32 + c;
  bf16x8 A = __builtin_bit_cast(bf16x8, dstfrag[(size_t)gj * 2 + h]);

  __syncthreads();

  const uint2* sf2 = (const uint2*)sh.sfrag;
  f32x16 zero = {};
  f32x16 mn;
  #pragma unroll
  for (int r = 0; r < 16; ++r) mn[r] = INFINITY;

  int t0r = 4 * w;  // per-wave rotation offset
  #pragma unroll 4
  for (int it = 0; it < 32; ++it) {
    int t = (it + t0r) & 31;
    uint2 u0 = sf2[t * 128 + lane];
    uint2 u1 = sf2[t * 128 + 64 + lane];
    bf16x8 Bf = __builtin_bit_cast(bf16x8, make_uint4(u0.x, u0.y, u1.x, u1.y));
    f32x16 d = __builtin_amdgcn_mfma_f32_32x32x16_bf16(A, Bf, zero, 0, 0, 0);
    #pragma unroll
    for (int r = 0; r < 16; ++r) mn[r] = fminf(mn[r], d[r]);
    // src-direction: fold my 16 rows for column c of this tile
    float t0 = fminf(fminf(d[0], d[1]), d[2]);
    float t1 = fminf(fminf(d[3], d[4]), d[5]);
    float t2 = fminf(fminf(d[6], d[7]), d[8]);
    float t3 = fminf(fminf(d[9], d[10]), d[11]);
    float t4 = fminf(fminf(d[12], d[13]), d[14]);
    float m = fminf(fminf(fminf(t0, t1), fminf(t2, t3)), fminf(t4, d[15]));
    atomicMin(&sh.smin[t * 32 + c], __float_as_uint(fmaxf(m, 0.f)));
  }

  // ---- src-direction flush
  __syncthreads();
  for (int p = tid; p < 1024; p += NT) {
    part_src[jp * BS + b * S + iq * 1024 + p] = __uint_as_float(sh.smin[p]);
  }
  __syncthreads();

  // ---- dst-direction: LDS transpose, stride 33 (2-way-free banks both sides)
  #pragma unroll
  for (int r = 0; r < 16; ++r) {
    int row = w * 32 + (r & 3) + 8 * (r >> 2) + 4 * h;  // 32x32 C/D layout
    red[row * 33 + c] = mn[r];
  }
  __syncthreads();
  {
    int row = tid >> 1, half = tid & 1;
    const float* rp = red + row * 33 + half * 16;
    float a0 = fminf(fminf(rp[0], rp[1]), rp[2]);
    float a1 = fminf(fminf(rp[3], rp[4]), rp[5]);
    float a2 = fminf(fminf(rp[6], rp[7]), rp[8]);
    float a3 = fminf(fminf(rp[9], rp[10]), rp[11]);
    float a4 = fminf(fminf(rp[12], rp[13]), rp[14]);
    float m = fminf(fminf(fminf(a0, a1), fminf(a2, a3)), fminf(a4, rp[15]));
    m = fminf(m, __shfl_xor(m, 1, 64));
    if (half == 0) {
      part_dst[iq * BS + b * S + jp * 256 + row] = fmaxf(m, 0.f);
    }
  }
}

// ---------------------------------------------------------------------------
// Reduce (merged): fold 16 src + 4 dst planes (elementwise min), sum, one
// atomicAdd per block (64 same-address atomics total — cheap per R7).
// ---------------------------------------------------------------------------
__global__ __launch_bounds__(256) void chamfer_reduce_kernel(
    const float* __restrict__ parts, float* __restrict__ out) {
  __shared__ float red[4];
  int tid = threadIdx.x;
  int i4 = blockIdx.x * 256 + tid;  // 16384 float4 slots = BS floats

  const float4* ps = (const float4*)parts;             // 16 src planes
  const float4* pd = (const float4*)(parts + 16 * BS); // 4 dst planes

  float4 ms = ps[i4];
  #pragma unroll
  for (int j = 1; j < 16; ++j) {
    float4 t = ps[j * (BS / 4) + i4];
    ms.x = fminf(ms.x, t.x); ms.y = fminf(ms.y, t.y);
    ms.z = fminf(ms.z, t.z); ms.w = fminf(ms.w, t.w);
  }
  float4 md = pd[i4];
  #pragma unroll
  for (int j = 1; j < 4; ++j) {
    float4 t = pd[j * (BS / 4) + i4];
    md.x = fminf(md.x, t.x); md.y = fminf(md.y, t.y);
    md.z = fminf(md.z, t.z); md.w = fminf(md.w, t.w);
  }
  float v = (ms.x + ms.y + ms.z + ms.w) + (md.x + md.y + md.z + md.w);
  v *= (1.0f / (float)BS);

  #pragma unroll
  for (int off = 32; off > 0; off >>= 1) v += __shfl_down(v, off, 64);
  if ((tid & 63) == 0) red[tid >> 6] = v;
  __syncthreads();
  if (tid == 0) atomicAdd(out, (red[0] + red[1]) + (red[2] + red[3]));
}

extern "C" void kernel_launch(void* const* d_in, const int* in_sizes, int n_in,
                              void* d_out, int out_size, void* d_ws, size_t ws_size,
                              hipStream_t stream) {
  const float* src_verts = (const float*)d_in[0];
  const float* dst_verts = (const float*)d_in[1];
  const int* src_idx = (const int*)d_in[2];
  const int* dst_idx = (const int*)d_in[3];
  float* out = (float*)d_out;

  float* parts = (float*)d_ws;
  float* part_src = parts;                        // [16][BS]
  float* part_dst = parts + 16 * BS;              // [4][BS]
  uint2* srcfrag = (uint2*)(parts + 21 * BS);     // BS*4 uint2 (2 MB)
  uint4* dstfrag = (uint4*)(parts + 29 * BS);     // BS*2 uint4 (2 MB)

  chamfer_prep_kernel<<<2 * BS / NT, NT, 0, stream>>>(
      src_verts, dst_verts, src_idx, dst_idx, srcfrag, dstfrag, out);

  // Launched TWICE (idempotent): delta vs R11 == T_mfma for attribution.
  chamfer_mfma_kernel<<<B * JP * 4, NT, 0, stream>>>(
      (const uint4*)srcfrag, dstfrag, part_src, part_dst);
  chamfer_mfma_kernel<<<B * JP * 4, NT, 0, stream>>>(
      (const uint4*)srcfrag, dstfrag, part_src, part_dst);

  chamfer_reduce_kernel<<<64, 256, 0, stream>>>(parts, out);
}

// Round 13
// 31.459 us; speedup vs baseline: 1.6726x; 1.6726x over previous
//
#include <hip/hip_runtime.h>
#include <hip/hip_bf16.h>
#include <math.h>

#define B 16
#define V 100000
#define S 4096
#define BS (B * S)      // 65536
#define NT 256          // mfma block threads (4 waves)
#define ONE_BF 0x3F80u  // 1.0 in bf16

typedef __attribute__((ext_vector_type(8))) short bf16x8;
typedef __attribute__((ext_vector_type(16))) float f32x16;

static __device__ __forceinline__ unsigned bft(float x) {
  return __float_as_uint(x) >> 16;  // truncating f32 -> bf16 bits
}
static __device__ __forceinline__ float bff(unsigned hbits) {
  return __uint_as_float(hbits << 16);
}
static __device__ __forceinline__ unsigned pk(unsigned lo, unsigned hi) {
  return (lo & 0xFFFFu) | (hi << 16);
}

// ws layout (floats):
//   part_src[16][BS] @ 0       (4 MB)
//   part_dst[4][BS]  @ 16*BS   (1 MB)
//   srcfrag          @ 21*BS   (2 MB)  B-frags, [tile][lane] uint4 (CONTIGUOUS)
//   dstfrag          @ 29*BS   (2 MB)  A-frags, [point][h] uint4

// ---------------------------------------------------------------------------
// Prep: per-point fragment content computed once. R13: src fragment is ONE
// contiguous uint4 per (point, h-lane) so the mfma loop needs a single
// ds_read_b128 (was 2x ds_read_b64 on split uint2s).
// ---------------------------------------------------------------------------
__global__ __launch_bounds__(512) void chamfer_prep_kernel(
    const float* __restrict__ src_verts, const float* __restrict__ dst_verts,
    const int* __restrict__ src_idx, const int* __restrict__ dst_idx,
    uint4* __restrict__ srcfrag, uint4* __restrict__ dstfrag,
    float* __restrict__ out) {
  int t = blockIdx.x * 512 + threadIdx.x;  // 0 .. 2*BS-1 (set uniform per block)
  if (t == 0) *out = 0.f;
  int set = t >> 16;
  int i = t & (BS - 1);  // b*S + p
  int b = i >> 12;

  const int* idx = set ? dst_idx : src_idx;
  const float* verts = set ? dst_verts : src_verts;
  int v = idx[i];
  v = v < 0 ? 0 : (v >= V ? V - 1 : v);
  const float* pv = verts + ((size_t)b * V + v) * 3;
  float x = pv[0], y = pv[1], z = pv[2];
  unsigned hx = bft(x), hy = bft(y), hz = bft(z);
  float n2 = x * x + y * y + z * z;
  unsigned n2h = bft(n2);
  unsigned n2l = bft(n2 - bff(n2h));

  if (set == 0) {
    // B-side (src): h=0 lane: k0-7 = [hx,hy,hz,lx,ly,lz,hx,hy]
    //               h=1 lane: k8-15 = [hz,s2h,s2l,1,1,0,0,0]
    unsigned lx = bft(x - bff(hx)), ly = bft(y - bff(hy)), lz = bft(z - bff(hz));
    int tile = i >> 5, c = i & 31;
    uint4* base = srcfrag + (size_t)tile * 64;  // 1024 B per tile
    base[c]      = make_uint4(pk(hx, hy), pk(hz, lx), pk(ly, lz), pk(hx, hy));
    base[32 + c] = make_uint4(pk(hz, n2h), pk(n2l, ONE_BF), pk(ONE_BF, 0u), 0u);
  } else {
    // A-side (dst): k0-7 = [mx,my,mz,mx,my,mz,nx,ny], k8-15 = [nz,1,1,d2h,d2l,0,0,0]
    unsigned mx = bft(-2.f * bff(hx)), my = bft(-2.f * bff(hy)), mz = bft(-2.f * bff(hz));
    unsigned nx = bft(-2.f * (x - bff(hx)));
    unsigned ny = bft(-2.f * (y - bff(hy)));
    unsigned nz = bft(-2.f * (z - bff(hz)));
    dstfrag[(size_t)i * 2]     = make_uint4(pk(mx, my), pk(mz, mx), pk(my, mz), pk(nx, ny));
    dstfrag[(size_t)i * 2 + 1] = make_uint4(pk(nz, ONE_BF), pk(ONE_BF, n2h), pk(n2l, 0u), 0u);
  }
}

// ---------------------------------------------------------------------------
// Fused kernel: block = (b, jp of 256 dst rows, iq of 1024 src), 256 threads
// = 4 waves; each wave owns TWO 32-row dst tiles (A0/A1) and reuses one
// ds_read_b128 B-fragment for both MFMAs -> LDS read ops per distance
// quartered vs R11 (1 b128 per 2048 distances). One atomicMin per iter.
// ---------------------------------------------------------------------------
__global__ __launch_bounds__(NT, 4) void chamfer_mfma_kernel(
    const uint4* __restrict__ srcfrag, const uint4* __restrict__ dstfrag,
    float* __restrict__ part_src, float* __restrict__ part_dst) {
  __shared__ struct {
    uint4 sfrag[2048];   // 32 KB: 32 tiles x 64 lanes x 16 B
    unsigned smin[1024]; // 4 KB
  } sh;
  // epilogue overlay: 256 rows x stride 33 floats = 33792 B (sfrag + smin head)
  float* red = (float*)sh.sfrag;

  int bid = blockIdx.x;
  int b = bid >> 6;
  int jp = (bid >> 2) & 15;
  int iq = bid & 3;
  int tid = threadIdx.x;

  // ---- stage: straight coalesced copy of this quarter's 32 KB fragment chunk
  const uint4* chunk = srcfrag + (size_t)(b * 128 + iq * 32) * 64;
  #pragma unroll
  for (int k = 0; k < 8; ++k) {
    sh.sfrag[tid + k * NT] = chunk[tid + k * NT];
  }
  #pragma unroll
  for (int k = 0; k < 4; ++k) sh.smin[tid + k * NT] = 0x7F800000u;  // +INF

  // ---- A-fragments: two dst tiles per wave, fixed all loop
  int w = tid >> 6;
  int lane = tid & 63;
  int c = lane & 31, h = lane >> 5;
  int gj = b * S + jp * 256 + w * 64 + c;
  bf16x8 A0 = __builtin_bit_cast(bf16x8, dstfrag[(size_t)gj * 2 + h]);
  bf16x8 A1 = __builtin_bit_cast(bf16x8, dstfrag[(size_t)(gj + 32) * 2 + h]);

  __syncthreads();

  f32x16 zero = {};
  f32x16 mn0, mn1;
  #pragma unroll
  for (int r = 0; r < 16; ++r) { mn0[r] = INFINITY; mn1[r] = INFINITY; }

  int t0r = 8 * w;  // per-wave rotation offset
  #pragma unroll 4
  for (int it = 0; it < 32; ++it) {
    int t = (it + t0r) & 31;
    bf16x8 Bf = __builtin_bit_cast(bf16x8, sh.sfrag[t * 64 + lane]);
    f32x16 d0 = __builtin_amdgcn_mfma_f32_32x32x16_bf16(A0, Bf, zero, 0, 0, 0);
    f32x16 d1 = __builtin_amdgcn_mfma_f32_32x32x16_bf16(A1, Bf, zero, 0, 0, 0);
    #pragma unroll
    for (int r = 0; r < 16; ++r) mn0[r] = fminf(mn0[r], d0[r]);
    #pragma unroll
    for (int r = 0; r < 16; ++r) mn1[r] = fminf(mn1[r], d1[r]);
    // src-direction: fold all 64 rows this wave computed for column (t, c)
    float t0 = fminf(fminf(d0[0], d0[1]), d0[2]);
    float t1 = fminf(fminf(d0[3], d0[4]), d0[5]);
    float t2 = fminf(fminf(d0[6], d0[7]), d0[8]);
    float t3 = fminf(fminf(d0[9], d0[10]), d0[11]);
    float t4 = fminf(fminf(d0[12], d0[13]), d0[14]);
    float s0 = fminf(fminf(d1[0], d1[1]), d1[2]);
    float s1 = fminf(fminf(d1[3], d1[4]), d1[5]);
    float s2 = fminf(fminf(d1[6], d1[7]), d1[8]);
    float s3 = fminf(fminf(d1[9], d1[10]), d1[11]);
    float s4 = fminf(fminf(d1[12], d1[13]), d1[14]);
    float m0 = fminf(fminf(fminf(t0, t1), fminf(t2, t3)), fminf(t4, d0[15]));
    float m1 = fminf(fminf(fminf(s0, s1), fminf(s2, s3)), fminf(s4, d1[15]));
    float m = fminf(m0, m1);
    atomicMin(&sh.smin[t * 32 + c], __float_as_uint(fmaxf(m, 0.f)));
  }

  // ---- src-direction flush
  __syncthreads();
  #pragma unroll
  for (int k = 0; k < 4; ++k) {
    int p = tid + k * NT;
    part_src[jp * BS + b * S + iq * 1024 + p] = __uint_as_float(sh.smin[p]);
  }
  __syncthreads();

  // ---- dst-direction: LDS transpose, stride 33 (conflict-free both sides)
  #pragma unroll
  for (int r = 0; r < 16; ++r) {
    int row = w * 64 + (r & 3) + 8 * (r >> 2) + 4 * h;  // 32x32 C/D layout
    red[row * 33 + c] = mn0[r];
    red[(row + 32) * 33 + c] = mn1[r];
  }
  __syncthreads();
  {
    int row = tid;  // 256 rows, 1 thread each; banks conflict-free (stride 33)
    const float* rp = red + row * 33;
    float a0 = fminf(fminf(rp[0], rp[1]), rp[2]);
    float a1 = fminf(fminf(rp[3], rp[4]), rp[5]);
    float a2 = fminf(fminf(rp[6], rp[7]), rp[8]);
    float a3 = fminf(fminf(rp[9], rp[10]), rp[11]);
    float a4 = fminf(fminf(rp[12], rp[13]), rp[14]);
    float a5 = fminf(fminf(rp[15], rp[16]), rp[17]);
    float a6 = fminf(fminf(rp[18], rp[19]), rp[20]);
    float a7 = fminf(fminf(rp[21], rp[22]), rp[23]);
    float a8 = fminf(fminf(rp[24], rp[25]), rp[26]);
    float a9 = fminf(fminf(rp[27], rp[28]), rp[29]);
    float aa = fminf(rp[30], rp[31]);
    float m = fminf(fminf(fminf(fminf(a0, a1), fminf(a2, a3)),
                          fminf(fminf(a4, a5), fminf(a6, a7))),
                    fminf(fminf(a8, a9), aa));
    part_dst[iq * BS + b * S + jp * 256 + row] = fmaxf(m, 0.f);
  }
}

// ---------------------------------------------------------------------------
// Reduce: fold 16 src + 4 dst planes (elementwise min), sum, one atomicAdd
// per block (64 total — proven cheap in R7).
// ---------------------------------------------------------------------------
__global__ __launch_bounds__(256) void chamfer_reduce_kernel(
    const float* __restrict__ parts, float* __restrict__ out) {
  __shared__ float red[4];
  int tid = threadIdx.x;
  int i4 = blockIdx.x * 256 + tid;  // 16384 float4 slots = BS floats

  const float4* ps = (const float4*)parts;             // 16 src planes
  const float4* pd = (const float4*)(parts + 16 * BS); // 4 dst planes

  float4 ms = ps[i4];
  #pragma unroll
  for (int j = 1; j < 16; ++j) {
    float4 t = ps[j * (BS / 4) + i4];
    ms.x = fminf(ms.x, t.x); ms.y = fminf(ms.y, t.y);
    ms.z = fminf(ms.z, t.z); ms.w = fminf(ms.w, t.w);
  }
  float4 md = pd[i4];
  #pragma unroll
  for (int j = 1; j < 4; ++j) {
    float4 t = pd[j * (BS / 4) + i4];
    md.x = fminf(md.x, t.x); md.y = fminf(md.y, t.y);
    md.z = fminf(md.z, t.z); md.w = fminf(md.w, t.w);
  }
  float v = (ms.x + ms.y + ms.z + ms.w) + (md.x + md.y + md.z + md.w);
  v *= (1.0f / (float)BS);

  #pragma unroll
  for (int off = 32; off > 0; off >>= 1) v += __shfl_down(v, off, 64);
  if ((tid & 63) == 0) red[tid >> 6] = v;
  __syncthreads();
  if (tid == 0) atomicAdd(out, (red[0] + red[1]) + (red[2] + red[3]));
}

extern "C" void kernel_launch(void* const* d_in, const int* in_sizes, int n_in,
                              void* d_out, int out_size, void* d_ws, size_t ws_size,
                              hipStream_t stream) {
  const float* src_verts = (const float*)d_in[0];
  const float* dst_verts = (const float*)d_in[1];
  const int* src_idx = (const int*)d_in[2];
  const int* dst_idx = (const int*)d_in[3];
  float* out = (float*)d_out;

  float* parts = (float*)d_ws;
  float* part_src = parts;                        // [16][BS]
  float* part_dst = parts + 16 * BS;              // [4][BS]
  uint4* srcfrag = (uint4*)(parts + 21 * BS);     // BS/32 tiles x 64 uint4 (2 MB)
  uint4* dstfrag = (uint4*)(parts + 29 * BS);     // BS*2 uint4 (2 MB)

  chamfer_prep_kernel<<<2 * BS / 512, 512, 0, stream>>>(
      src_verts, dst_verts, src_idx, dst_idx, srcfrag, dstfrag, out);

  chamfer_mfma_kernel<<<B * 16 * 4, NT, 0, stream>>>(
      srcfrag, dstfrag, part_src, part_dst);

  chamfer_reduce_kernel<<<64, 256, 0, stream>>>(parts, out);
}